// Round 2
// baseline (124.500 us; speedup 1.0000x reference)
//
#include <hip/hip_runtime.h>
#include <hip/hip_bf16.h>

// MaskedChamferDistance: B=64, NV=4096, NL=128, D=256, fp32 in/out.
// Round 2: LDS-free MFMA. Both A/B fragments of mfma_f32_16x16x32_bf16 are
// "8 contiguous bf16 from row (lane&15), k-chunk (lane>>4)*8" -> load straight
// from row-major global. V: fp32 read once, converted in-register (norms
// computed in-flight). L: pre-converted to bf16 by prep kernel (L2-resident).
// No 138KB LDS -> ~3 blocks/CU resident -> staging overlaps compute.

#define NB 64
#define NVC 4096
#define NLC 128
#define ND 256

using bf16x8 = __attribute__((ext_vector_type(8))) short;
using f32x4  = __attribute__((ext_vector_type(4))) float;

__device__ __forceinline__ unsigned short f2b(float f) {
  unsigned int u = __float_as_uint(f);
  u += 0x7FFFu + ((u >> 16) & 1u);          // round-to-nearest-even
  return (unsigned short)(u >> 16);
}
// monotone float -> uint transform so atomicMin(uint) == float min
__device__ __forceinline__ unsigned int fenc(float f) {
  unsigned int u = __float_as_uint(f);
  return (u & 0x80000000u) ? ~u : (u | 0x80000000u);
}
__device__ __forceinline__ float fdec(unsigned int u) {
  return (u & 0x80000000u) ? __uint_as_float(u & 0x7FFFFFFFu) : __uint_as_float(~u);
}

__device__ __forceinline__ bf16x8 pack8(float4 x, float4 y) {
  bf16x8 r;
  r[0] = (short)f2b(x.x); r[1] = (short)f2b(x.y);
  r[2] = (short)f2b(x.z); r[3] = (short)f2b(x.w);
  r[4] = (short)f2b(y.x); r[5] = (short)f2b(y.y);
  r[6] = (short)f2b(y.z); r[7] = (short)f2b(y.w);
  return r;
}

// ---- prep: L fp32->bf16 (row-major, ws) + |L|^2 norms + Nv = sum(mask) ----
__global__ __launch_bounds__(256) void chamfer_prep(
    const float* __restrict__ lf, const float* __restrict__ mask,
    unsigned short* __restrict__ lb, float* __restrict__ bn_g,
    float* __restrict__ nv_g)
{
  const int b = blockIdx.x, t = threadIdx.x;
  const int row0 = t >> 2, c4 = t & 3;
  #pragma unroll
  for (int p = 0; p < 2; ++p) {
    const int row = row0 + p * 64;
    const float* src = lf + ((size_t)b * NLC + row) * ND;
    unsigned short* dst = lb + ((size_t)b * NLC + row) * ND;
    float nrm = 0.f;
    #pragma unroll
    for (int i = 0; i < 16; ++i) {
      const int col = (c4 + 4 * i) * 4;
      float4 v = *reinterpret_cast<const float4*>(src + col);
      nrm += v.x * v.x + v.y * v.y + v.z * v.z + v.w * v.w;
      ushort4 h;
      h.x = f2b(v.x); h.y = f2b(v.y); h.z = f2b(v.z); h.w = f2b(v.w);
      *reinterpret_cast<ushort4*>(dst + col) = h;
    }
    nrm += __shfl_xor(nrm, 1);
    nrm += __shfl_xor(nrm, 2);
    if (c4 == 0) bn_g[(size_t)b * NLC + row] = nrm;
  }
  float s = 0.f;
  for (int i = t; i < NVC; i += 256) s += mask[(size_t)b * NVC + i];
  #pragma unroll
  for (int off = 32; off >= 1; off >>= 1) s += __shfl_xor(s, off);
  __shared__ float red[4];
  if ((t & 63) == 0) red[t >> 6] = s;
  __syncthreads();
  if (t == 0) nv_g[b] = red[0] + red[1] + red[2] + red[3];
}

// ---- main: one wave = 32 V-rows x all 128 L-cols, direct global MFMA ----
__global__ __launch_bounds__(256) void chamfer_main(
    const float* __restrict__ vf, const unsigned short* __restrict__ lb,
    const float* __restrict__ bn_g, const float* __restrict__ mask,
    unsigned int* __restrict__ colmin_g, float* __restrict__ rowsum_g)
{
  __shared__ float colmin_s[4][NLC];
  __shared__ float rowsum_s[4];

  const int t = threadIdx.x, wid = t >> 6, lane = t & 63;
  const int b = blockIdx.x >> 5;
  const int vw = (blockIdx.x & 31) * 128 + wid * 32;   // wave's first V row
  const int llo = lane & 15, lhi = lane >> 4;

  const float* arow0 = vf + ((size_t)b * NVC + vw + llo) * ND + lhi * 8;
  const float* arow1 = arow0 + 16 * ND;
  const unsigned short* lbb = lb + (size_t)b * NLC * ND + lhi * 8;

  f32x4 acc[2][8];
  #pragma unroll
  for (int m = 0; m < 2; ++m)
    #pragma unroll
    for (int n = 0; n < 8; ++n)
      acc[m][n] = (f32x4){0.f, 0.f, 0.f, 0.f};

  float n0 = 0.f, n1 = 0.f;   // in-flight |V_row|^2 partials (rows llo, llo+16)

  #pragma unroll 2
  for (int kk = 0; kk < 8; ++kk) {
    const int ko = kk * 32;
    float4 a00 = *reinterpret_cast<const float4*>(arow0 + ko);
    float4 a01 = *reinterpret_cast<const float4*>(arow0 + ko + 4);
    float4 a10 = *reinterpret_cast<const float4*>(arow1 + ko);
    float4 a11 = *reinterpret_cast<const float4*>(arow1 + ko + 4);
    n0 += a00.x*a00.x + a00.y*a00.y + a00.z*a00.z + a00.w*a00.w
        + a01.x*a01.x + a01.y*a01.y + a01.z*a01.z + a01.w*a01.w;
    n1 += a10.x*a10.x + a10.y*a10.y + a10.z*a10.z + a10.w*a10.w
        + a11.x*a11.x + a11.y*a11.y + a11.z*a11.z + a11.w*a11.w;
    bf16x8 af0 = pack8(a00, a01);
    bf16x8 af1 = pack8(a10, a11);
    #pragma unroll
    for (int n = 0; n < 8; ++n) {
      bf16x8 bfr = *reinterpret_cast<const bf16x8*>(lbb + ((n * 16 + llo) * ND + ko));
      acc[0][n] = __builtin_amdgcn_mfma_f32_16x16x32_bf16(af0, bfr, acc[0][n], 0, 0, 0);
      acc[1][n] = __builtin_amdgcn_mfma_f32_16x16x32_bf16(af1, bfr, acc[1][n], 0, 0, 0);
    }
  }

  // complete row norms across the 4 lhi k-chunks
  n0 += __shfl_xor(n0, 16); n0 += __shfl_xor(n0, 32);
  n1 += __shfl_xor(n1, 16); n1 += __shfl_xor(n1, 32);

  // redistribute: acc rows are (lane>>4)*4 + r; norms live at lane llo==row
  float av[2][4], mk[2][4];
  {
    const float mk0 = mask[(size_t)b * NVC + vw + llo];
    const float mk1 = mask[(size_t)b * NVC + vw + llo + 16];
    #pragma unroll
    for (int r = 0; r < 4; ++r) {
      const int src = lhi * 4 + r;
      av[0][r] = __shfl(n0, src);
      av[1][r] = __shfl(n1, src);
      mk[0][r] = __shfl(mk0, src);
      mk[1][r] = __shfl(mk1, src);
    }
  }
  float bncol[8];
  #pragma unroll
  for (int n = 0; n < 8; ++n) bncol[n] = bn_g[(size_t)b * NLC + n * 16 + llo];

  // ---- row mins (full: wave covers all 128 cols) + masked row-sum ----
  float rs = 0.f;
  #pragma unroll
  for (int m = 0; m < 2; ++m)
    #pragma unroll
    for (int r = 0; r < 4; ++r) {
      float v = bncol[0] - 2.f * acc[m][0][r];
      #pragma unroll
      for (int n = 1; n < 8; ++n)
        v = fminf(v, bncol[n] - 2.f * acc[m][n][r]);
      v = fminf(v, __shfl_xor(v, 1));
      v = fminf(v, __shfl_xor(v, 2));
      v = fminf(v, __shfl_xor(v, 4));
      v = fminf(v, __shfl_xor(v, 8));
      if (mk[m][r] != 0.f) rs += av[m][r] + v;
    }
  if (llo != 0) rs = 0.f;            // count each row once per lhi-group
  rs += __shfl_xor(rs, 16);
  rs += __shfl_xor(rs, 32);
  if (lane == 0) rowsum_s[wid] = rs;

  // ---- col mins over this wave's 32 rows (valid rows only) ----
  #pragma unroll
  for (int n = 0; n < 8; ++n) {
    float v = 3.0e38f;
    #pragma unroll
    for (int m = 0; m < 2; ++m)
      #pragma unroll
      for (int r = 0; r < 4; ++r) {
        const float s = av[m][r] - 2.f * acc[m][n][r];
        v = fminf(v, (mk[m][r] != 0.f) ? s : 3.0e38f);
      }
    v = fminf(v, __shfl_xor(v, 16));
    v = fminf(v, __shfl_xor(v, 32));
    if (lhi == 0) colmin_s[wid][n * 16 + llo] = v;
  }
  __syncthreads();

  if (t < NLC) {
    float cm = fminf(fminf(colmin_s[0][t], colmin_s[1][t]),
                     fminf(colmin_s[2][t], colmin_s[3][t]));
    atomicMin(colmin_g + (size_t)b * NLC + t, fenc(cm + bn_g[(size_t)b * NLC + t]));
  }
  if (t == 0)
    atomicAdd(rowsum_g + b, rowsum_s[0] + rowsum_s[1] + rowsum_s[2] + rowsum_s[3]);
}

// ---- finalize: out[b] = mean(colmin)/NL + rowsum/Nv ----
__global__ __launch_bounds__(128) void chamfer_fin(
    const unsigned int* __restrict__ colmin_g, const float* __restrict__ rowsum_g,
    const float* __restrict__ nv_g, float* __restrict__ out)
{
  const int b = blockIdx.x, t = threadIdx.x;
  __shared__ float red[2];
  float cs = fdec(colmin_g[(size_t)b * NLC + t]);
  #pragma unroll
  for (int off = 32; off >= 1; off >>= 1) cs += __shfl_xor(cs, off);
  if ((t & 63) == 0) red[t >> 6] = cs;
  __syncthreads();
  if (t == 0)
    out[b] = (red[0] + red[1]) / (float)NLC + rowsum_g[b] / nv_g[b];
}

extern "C" void kernel_launch(void* const* d_in, const int* in_sizes, int n_in,
                              void* d_out, int out_size, void* d_ws, size_t ws_size,
                              hipStream_t stream) {
  const float* vf   = (const float*)d_in[0];
  const float* lf   = (const float*)d_in[1];
  const float* mask = (const float*)d_in[2];
  float* out = (float*)d_out;

  char* ws = (char*)d_ws;
  unsigned short* lb = (unsigned short*)ws;                 // 64*128*256*2 = 4 MB
  size_t off = (size_t)NB * NLC * ND * sizeof(unsigned short);
  unsigned int* colmin = (unsigned int*)(ws + off);         // 32 KB
  off += (size_t)NB * NLC * sizeof(unsigned int);
  float* bn = (float*)(ws + off);                           // 32 KB
  off += (size_t)NB * NLC * sizeof(float);
  float* rowsum = (float*)(ws + off);                       // 256 B
  off += (size_t)NB * sizeof(float);
  float* nv = (float*)(ws + off);                           // 256 B

  hipMemsetAsync(colmin, 0xFF, (size_t)NB * NLC * sizeof(unsigned int), stream);
  hipMemsetAsync(rowsum, 0, (size_t)NB * sizeof(float), stream);

  chamfer_prep<<<dim3(NB), dim3(256), 0, stream>>>(lf, mask, lb, bn, nv);
  chamfer_main<<<dim3(NB * (NVC / 128)), dim3(256), 0, stream>>>(vf, lb, bn, mask, colmin, rowsum);
  chamfer_fin<<<dim3(NB), dim3(128), 0, stream>>>(colmin, rowsum, nv, out);
}

// Round 3
// 90.281 us; speedup vs baseline: 1.3790x; 1.3790x over previous
//
#include <hip/hip_runtime.h>
#include <hip/hip_bf16.h>

// MaskedChamferDistance: B=64, NV=4096, NL=128, D=256, fp32 in/out.
// Round 3: hybrid. B-fragments from LDS (L pre-converted bf16 by prep, staged
// 64KB/block); A-fragments direct from global fp32 (V read once, converted
// in-register, norms in-flight). 512 thr / 8 waves, wave = 16 rows x 128 cols,
// acc[1][8]=32 VGPR, launch_bounds(512,4) -> 2 blocks/CU, 4 waves/SIMD.

#define NB 64
#define NVC 4096
#define NLC 128
#define ND 256
#define LDV 264   // bf16 elems per LDS row: b128 reads land 8 dwords/bank = floor

using bf16x8 = __attribute__((ext_vector_type(8))) short;
using f32x4  = __attribute__((ext_vector_type(4))) float;

__device__ __forceinline__ unsigned short f2b(float f) {
  unsigned int u = __float_as_uint(f);
  u += 0x7FFFu + ((u >> 16) & 1u);          // round-to-nearest-even
  return (unsigned short)(u >> 16);
}
// monotone float -> uint transform so atomicMin(uint) == float min
__device__ __forceinline__ unsigned int fenc(float f) {
  unsigned int u = __float_as_uint(f);
  return (u & 0x80000000u) ? ~u : (u | 0x80000000u);
}
__device__ __forceinline__ float fdec(unsigned int u) {
  return (u & 0x80000000u) ? __uint_as_float(u & 0x7FFFFFFFu) : __uint_as_float(~u);
}

__device__ __forceinline__ bf16x8 pack8(float4 x, float4 y) {
  bf16x8 r;
  r[0] = (short)f2b(x.x); r[1] = (short)f2b(x.y);
  r[2] = (short)f2b(x.z); r[3] = (short)f2b(x.w);
  r[4] = (short)f2b(y.x); r[5] = (short)f2b(y.y);
  r[6] = (short)f2b(y.z); r[7] = (short)f2b(y.w);
  return r;
}

// ---- prep: L fp32->bf16 (row-major, ws) + |L|^2 norms + Nv = sum(mask) ----
__global__ __launch_bounds__(256) void chamfer_prep(
    const float* __restrict__ lf, const float* __restrict__ mask,
    unsigned short* __restrict__ lb, float* __restrict__ bn_g,
    float* __restrict__ nv_g)
{
  const int b = blockIdx.x, t = threadIdx.x;
  const int row0 = t >> 2, c4 = t & 3;
  #pragma unroll
  for (int p = 0; p < 2; ++p) {
    const int row = row0 + p * 64;
    const float* src = lf + ((size_t)b * NLC + row) * ND;
    unsigned short* dst = lb + ((size_t)b * NLC + row) * ND;
    float nrm = 0.f;
    #pragma unroll
    for (int i = 0; i < 16; ++i) {
      const int col = (c4 + 4 * i) * 4;
      float4 v = *reinterpret_cast<const float4*>(src + col);
      nrm += v.x * v.x + v.y * v.y + v.z * v.z + v.w * v.w;
      ushort4 h;
      h.x = f2b(v.x); h.y = f2b(v.y); h.z = f2b(v.z); h.w = f2b(v.w);
      *reinterpret_cast<ushort4*>(dst + col) = h;
    }
    nrm += __shfl_xor(nrm, 1);
    nrm += __shfl_xor(nrm, 2);
    if (c4 == 0) bn_g[(size_t)b * NLC + row] = nrm;
  }
  float s = 0.f;
  for (int i = t; i < NVC; i += 256) s += mask[(size_t)b * NVC + i];
  #pragma unroll
  for (int off = 32; off >= 1; off >>= 1) s += __shfl_xor(s, off);
  __shared__ float red[4];
  if ((t & 63) == 0) red[t >> 6] = s;
  __syncthreads();
  if (t == 0) nv_g[b] = red[0] + red[1] + red[2] + red[3];
}

// ---- main: 512 thr / 8 waves; wave = 16 V-rows x 128 L-cols ----
__global__ __launch_bounds__(512, 4) void chamfer_main(
    const float* __restrict__ vf, const unsigned short* __restrict__ lb,
    const float* __restrict__ bn_g, const float* __restrict__ mask,
    unsigned int* __restrict__ colmin_g, float* __restrict__ rowsum_g)
{
  __shared__ __attribute__((aligned(16))) unsigned short Llds[NLC * LDV];
  __shared__ float colmin_s[8][NLC];
  __shared__ float rowsum_s[8];

  const int t = threadIdx.x, wid = t >> 6, lane = t & 63;
  const int b = blockIdx.x >> 5;
  const int v0 = (blockIdx.x & 31) * 128;
  const int vw = v0 + wid * 16;
  const int llo = lane & 15, lhi = lane >> 4;

  // ---- stage L tile (128 x 256 bf16) L2 -> padded LDS, coalesced ----
  {
    const unsigned short* lbsrc = lb + (size_t)b * NLC * ND;
    #pragma unroll
    for (int i = 0; i < 8; ++i) {
      const int f = (i * 512 + t) * 8;     // element index, 16B per thread
      const int row = f >> 8, col = f & 255;
      *reinterpret_cast<bf16x8*>(&Llds[row * LDV + col]) =
          *reinterpret_cast<const bf16x8*>(&lbsrc[f]);
    }
  }
  __syncthreads();

  const float* arow = vf + ((size_t)b * NVC + vw + llo) * ND + lhi * 8;
  const int bbase = llo * LDV + lhi * 8;   // + n*16*LDV + kk*32 (imm-foldable)

  f32x4 acc[8];
  #pragma unroll
  for (int n = 0; n < 8; ++n) acc[n] = (f32x4){0.f, 0.f, 0.f, 0.f};

  float n0 = 0.f;   // in-flight |V_row|^2 partial (row vw+llo, k-chunk lhi)

  #pragma unroll 2
  for (int kk = 0; kk < 8; ++kk) {
    const int ko = kk * 32;
    float4 a00 = *reinterpret_cast<const float4*>(arow + ko);
    float4 a01 = *reinterpret_cast<const float4*>(arow + ko + 4);
    n0 += a00.x*a00.x + a00.y*a00.y + a00.z*a00.z + a00.w*a00.w
        + a01.x*a01.x + a01.y*a01.y + a01.z*a01.z + a01.w*a01.w;
    bf16x8 af0 = pack8(a00, a01);
    #pragma unroll
    for (int n = 0; n < 8; ++n) {
      bf16x8 bfr = *reinterpret_cast<const bf16x8*>(&Llds[bbase + n * 16 * LDV + ko]);
      acc[n] = __builtin_amdgcn_mfma_f32_16x16x32_bf16(af0, bfr, acc[n], 0, 0, 0);
    }
  }

  // complete row norms across the 4 lhi k-chunks
  n0 += __shfl_xor(n0, 16);
  n0 += __shfl_xor(n0, 32);

  // redistribute: acc rows are lhi*4 + r; norms/mask live at lane llo==row
  const float mk_l = mask[(size_t)b * NVC + vw + llo];
  float av[4], mk[4];
  #pragma unroll
  for (int r = 0; r < 4; ++r) {
    av[r] = __shfl(n0, lhi * 4 + r);
    mk[r] = __shfl(mk_l, lhi * 4 + r);
  }
  float bncol[8];
  #pragma unroll
  for (int n = 0; n < 8; ++n) bncol[n] = bn_g[(size_t)b * NLC + n * 16 + llo];

  // ---- row mins (wave covers all 128 cols) + masked row-sum ----
  float rs = 0.f;
  #pragma unroll
  for (int r = 0; r < 4; ++r) {
    float v = bncol[0] - 2.f * acc[0][r];
    #pragma unroll
    for (int n = 1; n < 8; ++n)
      v = fminf(v, bncol[n] - 2.f * acc[n][r]);
    v = fminf(v, __shfl_xor(v, 1));
    v = fminf(v, __shfl_xor(v, 2));
    v = fminf(v, __shfl_xor(v, 4));
    v = fminf(v, __shfl_xor(v, 8));
    if (llo == 0 && mk[r] != 0.f) rs += av[r] + v;
  }
  rs += __shfl_xor(rs, 16);
  rs += __shfl_xor(rs, 32);
  if (lane == 0) rowsum_s[wid] = rs;

  // ---- col mins over this wave's 16 rows (valid rows only) ----
  #pragma unroll
  for (int n = 0; n < 8; ++n) {
    float v = 3.0e38f;
    #pragma unroll
    for (int r = 0; r < 4; ++r) {
      const float s = av[r] - 2.f * acc[n][r];
      v = fminf(v, (mk[r] != 0.f) ? s : 3.0e38f);
    }
    v = fminf(v, __shfl_xor(v, 16));
    v = fminf(v, __shfl_xor(v, 32));
    if (lhi == 0) colmin_s[wid][n * 16 + llo] = v;
  }
  __syncthreads();

  if (t < NLC) {
    float cm = colmin_s[0][t];
    #pragma unroll
    for (int w = 1; w < 8; ++w) cm = fminf(cm, colmin_s[w][t]);
    atomicMin(colmin_g + (size_t)b * NLC + t, fenc(cm + bn_g[(size_t)b * NLC + t]));
  }
  if (t == 0) {
    float r2 = 0.f;
    #pragma unroll
    for (int w = 0; w < 8; ++w) r2 += rowsum_s[w];
    atomicAdd(rowsum_g + b, r2);
  }
}

// ---- finalize: out[b] = mean(colmin)/NL + rowsum/Nv ----
__global__ __launch_bounds__(128) void chamfer_fin(
    const unsigned int* __restrict__ colmin_g, const float* __restrict__ rowsum_g,
    const float* __restrict__ nv_g, float* __restrict__ out)
{
  const int b = blockIdx.x, t = threadIdx.x;
  __shared__ float red[2];
  float cs = fdec(colmin_g[(size_t)b * NLC + t]);
  #pragma unroll
  for (int off = 32; off >= 1; off >>= 1) cs += __shfl_xor(cs, off);
  if ((t & 63) == 0) red[t >> 6] = cs;
  __syncthreads();
  if (t == 0)
    out[b] = (red[0] + red[1]) / (float)NLC + rowsum_g[b] / nv_g[b];
}

extern "C" void kernel_launch(void* const* d_in, const int* in_sizes, int n_in,
                              void* d_out, int out_size, void* d_ws, size_t ws_size,
                              hipStream_t stream) {
  const float* vf   = (const float*)d_in[0];
  const float* lf   = (const float*)d_in[1];
  const float* mask = (const float*)d_in[2];
  float* out = (float*)d_out;

  char* ws = (char*)d_ws;
  unsigned short* lb = (unsigned short*)ws;                 // 4 MB
  size_t off = (size_t)NB * NLC * ND * sizeof(unsigned short);
  unsigned int* colmin = (unsigned int*)(ws + off);         // 32 KB
  off += (size_t)NB * NLC * sizeof(unsigned int);
  float* bn = (float*)(ws + off);                           // 32 KB
  off += (size_t)NB * NLC * sizeof(float);
  float* rowsum = (float*)(ws + off);                       // 256 B
  off += (size_t)NB * sizeof(float);
  float* nv = (float*)(ws + off);                           // 256 B

  hipMemsetAsync(colmin, 0xFF, (size_t)NB * NLC * sizeof(unsigned int), stream);
  hipMemsetAsync(rowsum, 0, (size_t)NB * sizeof(float), stream);

  chamfer_prep<<<dim3(NB), dim3(256), 0, stream>>>(lf, mask, lb, bn, nv);
  chamfer_main<<<dim3(NB * (NVC / 128)), dim3(512), 0, stream>>>(vf, lb, bn, mask, colmin, rowsum);
  chamfer_fin<<<dim3(NB), dim3(128), 0, stream>>>(colmin, rowsum, nv, out);
}

// Round 4
// 61.732 us; speedup vs baseline: 2.0168x; 1.4625x over previous
//
#include <hip/hip_runtime.h>
#include <hip/hip_bf16.h>

// MaskedChamferDistance: B=64, NV=4096, NL=128, D=256, fp32 in/out.
// Round 4: persistent-resident main (512 blocks = 2/CU), 4 chunks of 128 V-rows
// per block over one L-stage; zero atomics / zero memsets (disjoint partials in
// ws, reduced by fin). Inner loop unchanged from round 3 (LDS-B + global-A).

#define NB 64
#define NVC 4096
#define NLC 128
#define ND 256
#define LDV 264   // bf16 elems per LDS row (16B-aligned rows)

using bf16x8 = __attribute__((ext_vector_type(8))) short;
using f32x4  = __attribute__((ext_vector_type(4))) float;

__device__ __forceinline__ unsigned short f2b(float f) {
  unsigned int u = __float_as_uint(f);
  u += 0x7FFFu + ((u >> 16) & 1u);          // round-to-nearest-even
  return (unsigned short)(u >> 16);
}
__device__ __forceinline__ bf16x8 pack8(float4 x, float4 y) {
  bf16x8 r;
  r[0] = (short)f2b(x.x); r[1] = (short)f2b(x.y);
  r[2] = (short)f2b(x.z); r[3] = (short)f2b(x.w);
  r[4] = (short)f2b(y.x); r[5] = (short)f2b(y.y);
  r[6] = (short)f2b(y.z); r[7] = (short)f2b(y.w);
  return r;
}

// ---- prep: L fp32->bf16 + |L|^2 norms. 256 blocks = 64 b x 4 parts ----
__global__ __launch_bounds__(256) void chamfer_prep(
    const float* __restrict__ lf, unsigned short* __restrict__ lb,
    float* __restrict__ bn_g)
{
  const int b = blockIdx.x >> 2, part = blockIdx.x & 3;
  const int t = threadIdx.x;
  const int row = part * 32 + (t >> 3), c8 = t & 7;
  const float* src = lf + ((size_t)b * NLC + row) * ND;
  unsigned short* dst = lb + ((size_t)b * NLC + row) * ND;
  float nrm = 0.f;
  #pragma unroll
  for (int i = 0; i < 8; ++i) {
    const int col = (c8 + 8 * i) * 4;
    float4 v = *reinterpret_cast<const float4*>(src + col);
    nrm += v.x * v.x + v.y * v.y + v.z * v.z + v.w * v.w;
    ushort4 h;
    h.x = f2b(v.x); h.y = f2b(v.y); h.z = f2b(v.z); h.w = f2b(v.w);
    *reinterpret_cast<ushort4*>(dst + col) = h;
  }
  nrm += __shfl_xor(nrm, 1);
  nrm += __shfl_xor(nrm, 2);
  nrm += __shfl_xor(nrm, 4);
  if (c8 == 0) bn_g[(size_t)b * NLC + row] = nrm;
}

// ---- main: 512 blocks (b, 512-row slice); 8 waves; wave = 16 rows x 128 cols,
//      4 chunks back-to-back over one LDS L-stage; disjoint partial outputs ----
__global__ __launch_bounds__(512, 4) void chamfer_main(
    const float* __restrict__ vf, const unsigned short* __restrict__ lb,
    const float* __restrict__ bn_g, const float* __restrict__ mask,
    float* __restrict__ colmin_part, float* __restrict__ rowsum_part,
    float* __restrict__ nv_part)
{
  __shared__ __attribute__((aligned(16))) unsigned short Llds[NLC * LDV];
  __shared__ float colmin_s[8][NLC];
  __shared__ float rowsum_s[8];
  __shared__ float msum_s[8];

  const int t = threadIdx.x, wid = t >> 6, lane = t & 63;
  const int b = blockIdx.x >> 3;
  const int slice = blockIdx.x & 7;            // 512-row slice of batch b
  const int llo = lane & 15, lhi = lane >> 4;

  // ---- stage L tile (128 x 256 bf16) -> padded LDS, coalesced ----
  {
    const unsigned short* lbsrc = lb + (size_t)b * NLC * ND;
    #pragma unroll
    for (int i = 0; i < 8; ++i) {
      const int f = (i * 512 + t) * 8;
      const int row = f >> 8, col = f & 255;
      *reinterpret_cast<bf16x8*>(&Llds[row * LDV + col]) =
          *reinterpret_cast<const bf16x8*>(&lbsrc[f]);
    }
  }

  float bncol[8];
  #pragma unroll
  for (int n = 0; n < 8; ++n) bncol[n] = bn_g[(size_t)b * NLC + n * 16 + llo];

  __syncthreads();

  const int bbase = llo * LDV + lhi * 8;

  float cmin[8];
  #pragma unroll
  for (int n = 0; n < 8; ++n) cmin[n] = 3.0e38f;
  float rs = 0.f, msum = 0.f;

  for (int c = 0; c < 4; ++c) {
    const int vbase = slice * 512 + c * 128 + wid * 16;
    const float* arow = vf + ((size_t)b * NVC + vbase + llo) * ND + lhi * 8;

    f32x4 acc[8];
    #pragma unroll
    for (int n = 0; n < 8; ++n) acc[n] = (f32x4){0.f, 0.f, 0.f, 0.f};
    float n0 = 0.f;

    #pragma unroll 2
    for (int kk = 0; kk < 8; ++kk) {
      const int ko = kk * 32;
      float4 a00 = *reinterpret_cast<const float4*>(arow + ko);
      float4 a01 = *reinterpret_cast<const float4*>(arow + ko + 4);
      n0 += a00.x*a00.x + a00.y*a00.y + a00.z*a00.z + a00.w*a00.w
          + a01.x*a01.x + a01.y*a01.y + a01.z*a01.z + a01.w*a01.w;
      bf16x8 af0 = pack8(a00, a01);
      #pragma unroll
      for (int n = 0; n < 8; ++n) {
        bf16x8 bfr = *reinterpret_cast<const bf16x8*>(&Llds[bbase + n * 16 * LDV + ko]);
        acc[n] = __builtin_amdgcn_mfma_f32_16x16x32_bf16(af0, bfr, acc[n], 0, 0, 0);
      }
    }

    // complete row norms across 4 lhi k-chunks
    n0 += __shfl_xor(n0, 16);
    n0 += __shfl_xor(n0, 32);

    // redistribute to C-layout rows: row = lhi*4 + r
    const float mk_l = mask[(size_t)b * NVC + vbase + llo];
    float av[4], mk[4];
    #pragma unroll
    for (int r = 0; r < 4; ++r) {
      av[r] = __shfl(n0, lhi * 4 + r);
      mk[r] = __shfl(mk_l, lhi * 4 + r);
    }

    // row mins (wave covers all 128 cols) + masked row-sum + mask count
    #pragma unroll
    for (int r = 0; r < 4; ++r) {
      float v = bncol[0] - 2.f * acc[0][r];
      #pragma unroll
      for (int n = 1; n < 8; ++n)
        v = fminf(v, bncol[n] - 2.f * acc[n][r]);
      v = fminf(v, __shfl_xor(v, 1));
      v = fminf(v, __shfl_xor(v, 2));
      v = fminf(v, __shfl_xor(v, 4));
      v = fminf(v, __shfl_xor(v, 8));
      if (llo == 0 && mk[r] != 0.f) { rs += av[r] + v; msum += 1.f; }
    }

    // col mins over this chunk's 16 rows (valid rows only), in-lane accumulate
    #pragma unroll
    for (int n = 0; n < 8; ++n) {
      float v = cmin[n];
      #pragma unroll
      for (int r = 0; r < 4; ++r) {
        const float s = av[r] - 2.f * acc[n][r];
        v = fminf(v, (mk[r] != 0.f) ? s : 3.0e38f);
      }
      cmin[n] = v;
    }
  }

  // ---- wave-level finishes ----
  rs += __shfl_xor(rs, 16);   rs += __shfl_xor(rs, 32);
  msum += __shfl_xor(msum, 16); msum += __shfl_xor(msum, 32);
  #pragma unroll
  for (int n = 0; n < 8; ++n) {
    float v = cmin[n];
    v = fminf(v, __shfl_xor(v, 16));
    v = fminf(v, __shfl_xor(v, 32));
    if (lhi == 0) colmin_s[wid][n * 16 + llo] = v;
  }
  if (lane == 0) { rowsum_s[wid] = rs; msum_s[wid] = msum; }
  __syncthreads();

  const size_t pidx = (size_t)b * 8 + slice;
  if (t < NLC) {
    float cm = colmin_s[0][t];
    #pragma unroll
    for (int w = 1; w < 8; ++w) cm = fminf(cm, colmin_s[w][t]);
    colmin_part[pidx * NLC + t] = cm;
  }
  if (t == 0) {
    float r2 = 0.f, m2 = 0.f;
    #pragma unroll
    for (int w = 0; w < 8; ++w) { r2 += rowsum_s[w]; m2 += msum_s[w]; }
    rowsum_part[pidx] = r2;
    nv_part[pidx] = m2;
  }
}

// ---- fin: reduce 8 partials per batch; out[b] ----
__global__ __launch_bounds__(128) void chamfer_fin(
    const float* __restrict__ colmin_part, const float* __restrict__ rowsum_part,
    const float* __restrict__ nv_part, const float* __restrict__ bn_g,
    float* __restrict__ out)
{
  const int b = blockIdx.x, t = threadIdx.x;
  __shared__ float red[2];
  float cm = 3.0e38f;
  #pragma unroll
  for (int p = 0; p < 8; ++p)
    cm = fminf(cm, colmin_part[((size_t)b * 8 + p) * NLC + t]);
  float cs = cm + bn_g[(size_t)b * NLC + t];
  #pragma unroll
  for (int off = 32; off >= 1; off >>= 1) cs += __shfl_xor(cs, off);
  if ((t & 63) == 0) red[t >> 6] = cs;
  __syncthreads();
  if (t == 0) {
    float rsum = 0.f, nv = 0.f;
    #pragma unroll
    for (int p = 0; p < 8; ++p) {
      rsum += rowsum_part[(size_t)b * 8 + p];
      nv   += nv_part[(size_t)b * 8 + p];
    }
    out[b] = (red[0] + red[1]) / (float)NLC + rsum / nv;
  }
}

extern "C" void kernel_launch(void* const* d_in, const int* in_sizes, int n_in,
                              void* d_out, int out_size, void* d_ws, size_t ws_size,
                              hipStream_t stream) {
  const float* vf   = (const float*)d_in[0];
  const float* lf   = (const float*)d_in[1];
  const float* mask = (const float*)d_in[2];
  float* out = (float*)d_out;

  char* ws = (char*)d_ws;
  unsigned short* lb = (unsigned short*)ws;                 // 4 MB
  size_t off = (size_t)NB * NLC * ND * sizeof(unsigned short);
  float* bn = (float*)(ws + off);                           // 32 KB
  off += (size_t)NB * NLC * sizeof(float);
  float* colmin_part = (float*)(ws + off);                  // 64*8*128*4 = 256 KB
  off += (size_t)NB * 8 * NLC * sizeof(float);
  float* rowsum_part = (float*)(ws + off);                  // 2 KB
  off += (size_t)NB * 8 * sizeof(float);
  float* nv_part = (float*)(ws + off);                      // 2 KB

  chamfer_prep<<<dim3(NB * 4), dim3(256), 0, stream>>>(lf, lb, bn);
  chamfer_main<<<dim3(NB * 8), dim3(512), 0, stream>>>(vf, lb, bn, mask,
                                                       colmin_part, rowsum_part, nv_part);
  chamfer_fin<<<dim3(NB), dim3(128), 0, stream>>>(colmin_part, rowsum_part, nv_part, bn, out);
}